// Round 13
// baseline (158.619 us; speedup 1.0000x reference)
//
#include <hip/hip_runtime.h>
#include <math.h>

// Problem constants (from reference)
#define N_NODES 10000
#define K_NB    32
#define D       256    // per-group input/output feature dim
#define XD      512    // x / t / out row stride (2 groups concatenated)

typedef __attribute__((ext_vector_type(8))) short  short8;  // 8 bf16 (4 VGPR) MFMA A/B frag
typedef __attribute__((ext_vector_type(4))) float  f32x4;   // MFMA C/D frag

typedef __attribute__((address_space(1))) const unsigned int g_u32;
typedef __attribute__((address_space(3))) unsigned int       l_u32;

// explicit global->LDS DMA, 16B per lane (m97 path; scheduler cannot sink it).
// lds dest must be WAVE-UNIFORM; HW scatters lane i to dest + i*16.
__device__ __forceinline__ void gld_lds16(const void* g, void* l) {
    __builtin_amdgcn_global_load_lds((g_u32*)g, (l_u32*)l, 16, 0, 0);
}

__device__ __forceinline__ float clip1(float v) { return fminf(fmaxf(v, -1.f), 1.f); }

__device__ __forceinline__ unsigned int bf16_rne(float f) {   // RNE f32 -> bf16 bits
    unsigned int u = __float_as_uint(f);
    return (u + 0x7FFFu + ((u >> 16) & 1u)) >> 16;
}
__device__ __forceinline__ float bf16f(unsigned int h) { return __uint_as_float(h << 16); }
__device__ __forceinline__ float blo(unsigned int u) { return __uint_as_float(u << 16); }
__device__ __forceinline__ float bhif(unsigned int u) { return __uint_as_float(u & 0xFFFF0000u); }

// 8 consecutive-k fp32 -> hi/lo bf16 (Markidis split), packed 8x bf16 per uint4
__device__ __forceinline__ void cvt8(float4 A, float4 B, uint4& hi, uint4& lo) {
    const float v[8] = {A.x, A.y, A.z, A.w, B.x, B.y, B.z, B.w};
    unsigned int h[8], q[8];
    #pragma unroll
    for (int i = 0; i < 8; ++i) {
        h[i] = bf16_rne(v[i]);
        q[i] = bf16_rne(v[i] - bf16f(h[i]));
    }
    hi = make_uint4(h[0] | (h[1] << 16), h[2] | (h[3] << 16),
                    h[4] | (h[5] << 16), h[6] | (h[7] << 16));
    lo = make_uint4(q[0] | (q[1] << 16), q[2] | (q[3] << 16),
                    q[4] | (q[5] << 16), q[6] | (q[7] << 16));
}

// Kernel 0: one-time W -> bf16 hi/lo split (2 groups x 256x256, 8 elems/thread).
__global__ __launch_bounds__(256)
void conv_w(const float* __restrict__ W1, const float* __restrict__ W2,
            unsigned short* __restrict__ Whi, unsigned short* __restrict__ Wlo)
{
    const int u    = blockIdx.x * 256 + threadIdx.x;   // 0..16383 (oct index)
    const int gidx = u >> 13;                          // 8192 octs per group
    const int rem  = u & 8191;
    const float* __restrict__ W = gidx ? W2 : W1;
    const float4 f0 = *(const float4*)&W[rem * 8];
    const float4 f1 = *(const float4*)&W[rem * 8 + 4];
    uint4 hi, lo;
    cvt8(f0, f1, hi, lo);
    *(uint4*)&Whi[gidx * 65536 + rem * 8] = hi;
    *(uint4*)&Wlo[gidx * 65536 + rem * 8] = lo;
}

// Kernel 1: t16[row][g*256+o] = bf16( clip( (x_g@W^T)[row][o]*softmax(a)[o] ) )
// Round-13 hybrid (from r12 evidence: per-chunk LDS round-trip + 16 barriers
// was overhead; W is L2-resident and r9 proved direct B loads are fine):
//  - x tile (32 rows x 256 k fp32, 32 KB) staged ONCE via 8 global_load_lds
//    issued BEFORE the softmax (DMA overlaps it; softmax barriers drain it).
//    Granule swizzle gk^(row&7) on source+read (rule 21): lanes 0-7 span all
//    32 banks, 2-way alias = free.
//  - kc loop: 2 swizzled ds_read_b128 + cvt8 + 8 per-lane B loads (L2) +
//    12 MFMA, fully unrolled, ZERO barriers.  16 waves/CU hide B latency.
// C/D map: m89-verified col=lane&15, row=(lane>>4)*4+reg (validated r6-r12).
__global__ __launch_bounds__(256, 4)
void gemm_mfma(const float* __restrict__ x,
               const float* __restrict__ a1, const float* __restrict__ a2,
               const unsigned short* __restrict__ Whi,
               const unsigned short* __restrict__ Wlo,
               unsigned short* __restrict__ t16)
{
    const int slab = blockIdx.x;            // 32-row slab, 0..312 (last 16 phantom)
    const int cz   = blockIdx.y;            // col half (128 cols)
    const int g    = blockIdx.z;
    const float* __restrict__ a = g ? a2 : a1;
    const int tid = threadIdx.x;
    const int w   = tid >> 6;
    const int l   = tid & 63;

    __shared__ float As[32 * 256];          // 32 KB [row][k] fp32, granule-swizzled
    __shared__ float fwL[D];
    __shared__ float red[16];

    // ---- issue the full A-tile stage FIRST (8 DMA calls; overlap softmax) ----
    // call j: dest row = 4j + w, granule = lane (linear dest);
    // source granule = lane ^ (row&7)  (inverse swizzle on the global side).
    {
        const int row  = (w & 3);                      // w = tid>>6
        #pragma unroll
        for (int j = 0; j < 8; ++j) {
            const int rloc = j * 4 + row;
            int grow = slab * 32 + rloc;
            if (grow > N_NODES - 1) grow = N_NODES - 1;   // clamp phantom rows
            const int sg = l ^ (rloc & 7);                // per-lane src granule
            gld_lds16(&x[(size_t)grow * XD + g * D + sg * 4],
                      (char*)As + j * 4096 + w * 1024);
        }
    }

    // ---- softmax(a) over 256 (block == 256 threads), redundantly per block ----
    {
        float v = a[tid];
        float m = v;
        #pragma unroll
        for (int o = 32; o; o >>= 1) m = fmaxf(m, __shfl_xor(m, o));
        if ((tid & 63) == 0) red[tid >> 6] = m;
        __syncthreads();
        m = fmaxf(fmaxf(red[0], red[1]), fmaxf(red[2], red[3]));
        float e = expf(v - m);
        float s = e;
        #pragma unroll
        for (int o = 32; o; o >>= 1) s += __shfl_xor(s, o);
        if ((tid & 63) == 0) red[4 + (tid >> 6)] = s;
        __syncthreads();
        s = red[4] + red[5] + red[6] + red[7];
        fwL[tid] = e / s;
    }
    __syncthreads();                         // fwL + staged A visible to all

    const unsigned short* __restrict__ WhiG = Whi + (g << 16);
    const unsigned short* __restrict__ WloG = Wlo + (g << 16);

    f32x4 acc[4];
    #pragma unroll
    for (int i = 0; i < 4; ++i) acc[i] = (f32x4){0.f, 0.f, 0.f, 0.f};

    const int arow_l = 16 * (w >> 1) + (l & 15);      // wave's A row in tile
    const int s      = l >> 4;                        // k-slot 0..3 (8 elems)
    const int ct0    = (w & 1) * 4;                   // wave's 4 col-tiles
    const char* Arow = (const char*)As + arow_l * 1024;
    const int   rz   = arow_l & 7;                    // read-side swizzle key

    #pragma unroll
    for (int kc = 0; kc < 8; ++kc) {
        const int kbase = kc * 32 + 8 * s;
        // A fragment: 2 swizzled b128 reads -> cvt8
        const int g0 = (kc * 8 + 2 * s)     ^ rz;
        const int g1 = (kc * 8 + 2 * s + 1) ^ rz;
        const float4 xa = *(const float4*)(Arow + g0 * 16);
        const float4 xb = *(const float4*)(Arow + g1 * 16);
        uint4 ahi, alo;
        cvt8(xa, xb, ahi, alo);
        const short8 ah = __builtin_bit_cast(short8, ahi);
        const short8 al = __builtin_bit_cast(short8, alo);

        #pragma unroll
        for (int i = 0; i < 4; ++i) {
            const int brow = cz * 128 + (ct0 + i) * 16 + (l & 15);
            const short8 bh = __builtin_bit_cast(short8,
                *(const uint4*)&WhiG[brow * 256 + kbase]);
            const short8 bl = __builtin_bit_cast(short8,
                *(const uint4*)&WloG[brow * 256 + kbase]);
            acc[i] = __builtin_amdgcn_mfma_f32_16x16x32_bf16(ah, bh, acc[i], 0, 0, 0);
            acc[i] = __builtin_amdgcn_mfma_f32_16x16x32_bf16(al, bh, acc[i], 0, 0, 0);
            acc[i] = __builtin_amdgcn_mfma_f32_16x16x32_bf16(ah, bl, acc[i], 0, 0, 0);
        }
    }

    // ---- epilogue: fw scale + hardtanh + bf16 store ----
    #pragma unroll
    for (int i = 0; i < 4; ++i) {
        const int   col = cz * 128 + (ct0 + i) * 16 + (l & 15);
        const float fw  = fwL[col];
        #pragma unroll
        for (int r = 0; r < 4; ++r) {
            const int row = slab * 32 + 16 * (w >> 1) + (l >> 4) * 4 + r;
            if (row < N_NODES)
                t16[(size_t)row * XD + g * D + col] =
                    (unsigned short)bf16_rne(clip1(acc[i][r] * fw));
        }
    }
}

// Kernel 2: SINGLE-PASS gather + Gaussian attention + aggregation, bf16 t.
// BYTE-IDENTICAL to round 9 (attribution: only gemm changes this round).
__global__ __launch_bounds__(256, 8)
void gat_aggregate(const unsigned short* __restrict__ t16,
                   const int* __restrict__ graph, float* __restrict__ out)
{
    const int n   = blockIdx.x;
    const int g   = blockIdx.y;
    const int tid = threadIdx.x;
    const int w   = tid >> 6;
    const int l   = tid & 63;

    __shared__ float part[4][D];    // per-wave partial weighted sums (4 KB)
    __shared__ float Ssh[4];        // per-wave partial exp-sums

    int rows[8];
    #pragma unroll
    for (int kk = 0; kk < 8; ++kk)
        rows[kk] = graph[(size_t)n * K_NB + (w + kk * 4)];

    const size_t gcol = (size_t)g * D + 4 * l;           // bf16 element index
    const uint2 ov = *(const uint2*)&t16[(size_t)n * XD + gcol];
    const float o0 = blo(ov.x), o1 = bhif(ov.x), o2 = blo(ov.y), o3 = bhif(ov.y);

    // batch all 8 gather loads before any use (8 outstanding 8B / lane)
    uint2 nbu[8];
    #pragma unroll
    for (int kk = 0; kk < 8; ++kk)
        nbu[kk] = *(const uint2*)&t16[(size_t)rows[kk] * XD + gcol];

    // unpack once; per-lane partial d2 for each of this wave's 8 k's
    float nf[8][4];
    float d2p[8];
    #pragma unroll
    for (int kk = 0; kk < 8; ++kk) {
        nf[kk][0] = blo(nbu[kk].x); nf[kk][1] = bhif(nbu[kk].x);
        nf[kk][2] = blo(nbu[kk].y); nf[kk][3] = bhif(nbu[kk].y);
        const float dx = o0 - nf[kk][0], dy = o1 - nf[kk][1];
        const float dz = o2 - nf[kk][2], dw = o3 - nf[kk][3];
        d2p[kk] = dx * dx + dy * dy + dz * dz + dw * dw;
    }

    // reduce-scatter over lane bits 0..2: lane l ends owning kk = l&7
    const bool b0 = l & 1, b1 = l & 2, b2 = l & 4;
    float u[4];
    #pragma unroll
    for (int i = 0; i < 4; ++i) {
        const float give = b0 ? d2p[2 * i] : d2p[2 * i + 1];
        const float keep = b0 ? d2p[2 * i + 1] : d2p[2 * i];
        u[i] = keep + __shfl_xor(give, 1);
    }
    float v[2];
    #pragma unroll
    for (int i = 0; i < 2; ++i) {
        const float give = b1 ? u[2 * i] : u[2 * i + 1];
        const float keep = b1 ? u[2 * i + 1] : u[2 * i];
        v[i] = keep + __shfl_xor(give, 2);
    }
    float d2 = (b2 ? v[1] : v[0]) + __shfl_xor(b2 ? v[0] : v[1], 4);
    // finish the 64-lane sum (kk = l&7 fixed, sum over the 8 lane-groups)
    d2 += __shfl_xor(d2, 8);
    d2 += __shfl_xor(d2, 16);
    d2 += __shfl_xor(d2, 32);

    const float e = __expf(-d2);          // ONE exp per lane (owns kk = l&7)

    // wave's exp-sum over its 8 k's (uniform in all lanes after 3 steps)
    float Sw = e;
    Sw += __shfl_xor(Sw, 1);
    Sw += __shfl_xor(Sw, 2);
    Sw += __shfl_xor(Sw, 4);

    // gather the 8 e's (ds_bpermute — LDS pipe) and accumulate
    const int base = l & 56;
    float4 p = make_float4(0.f, 0.f, 0.f, 0.f);
    #pragma unroll
    for (int kk = 0; kk < 8; ++kk) {
        const float ak = __shfl(e, base + kk);
        p.x += ak * nf[kk][0]; p.y += ak * nf[kk][1];
        p.z += ak * nf[kk][2]; p.w += ak * nf[kk][3];
    }

    *(float4*)&part[w][4 * l] = p;
    if (l == 0) Ssh[w] = Sw;
    __syncthreads();

    const float rS = 1.f / (Ssh[0] + Ssh[1] + Ssh[2] + Ssh[3]);
    const float y  = (part[0][tid] + part[1][tid] + part[2][tid] + part[3][tid]) * rS;
    out[(size_t)n * XD + (size_t)g * D + tid] = y;
}

extern "C" void kernel_launch(void* const* d_in, const int* in_sizes, int n_in,
                              void* d_out, int out_size, void* d_ws, size_t ws_size,
                              hipStream_t stream) {
    const float* x     = (const float*)d_in[0];
    const float* W1    = (const float*)d_in[1];
    const float* a1    = (const float*)d_in[2];
    const float* W2    = (const float*)d_in[3];
    const float* a2    = (const float*)d_in[4];
    const int*   graph = (const int*)d_in[5];
    float* out = (float*)d_out;

    // workspace layout: t16 bf16 (10.24 MB) | Whi (256 KB) | Wlo (256 KB)
    unsigned short* t16 = (unsigned short*)d_ws;
    unsigned short* Whi = t16 + (size_t)N_NODES * XD;
    unsigned short* Wlo = Whi + 2 * 65536;

    conv_w<<<64, 256, 0, stream>>>(W1, W2, Whi, Wlo);

    dim3 grid1(313, 2, 2);                            // (32-row slab, colhalf, group)
    gemm_mfma<<<grid1, 256, 0, stream>>>(x, a1, a2, Whi, Wlo, t16);

    dim3 grid2(N_NODES, 2);
    gat_aggregate<<<grid2, 256, 0, stream>>>(t16, graph, out);
}

// Round 14
// 128.715 us; speedup vs baseline: 1.2323x; 1.2323x over previous
//
#include <hip/hip_runtime.h>
#include <math.h>

// Problem constants (from reference)
#define N_NODES 10000
#define K_NB    32
#define D       256    // per-group input/output feature dim
#define XD      512    // x / t / out row stride (2 groups concatenated)

typedef __attribute__((ext_vector_type(8))) short  short8;  // 8 bf16 (4 VGPR) MFMA A/B frag
typedef __attribute__((ext_vector_type(4))) float  f32x4;   // MFMA C/D frag

typedef __attribute__((address_space(1))) const unsigned int g_u32;
typedef __attribute__((address_space(3))) unsigned int       l_u32;

// explicit global->LDS DMA, 16B per lane (m97 path; scheduler cannot sink it).
// lds dest must be WAVE-UNIFORM; HW scatters lane i to dest + i*16.
__device__ __forceinline__ void gld_lds16(const void* g, void* l) {
    __builtin_amdgcn_global_load_lds((g_u32*)g, (l_u32*)l, 16, 0, 0);
}

__device__ __forceinline__ float clip1(float v) { return fminf(fmaxf(v, -1.f), 1.f); }

__device__ __forceinline__ unsigned int bf16_rne(float f) {   // RNE f32 -> bf16 bits
    unsigned int u = __float_as_uint(f);
    return (u + 0x7FFFu + ((u >> 16) & 1u)) >> 16;
}
__device__ __forceinline__ float bf16f(unsigned int h) { return __uint_as_float(h << 16); }
__device__ __forceinline__ float blo(unsigned int u) { return __uint_as_float(u << 16); }
__device__ __forceinline__ float bhif(unsigned int u) { return __uint_as_float(u & 0xFFFF0000u); }

// 8 consecutive-k fp32 -> hi/lo bf16 (Markidis split), packed 8x bf16 per uint4
__device__ __forceinline__ void cvt8(float4 A, float4 B, uint4& hi, uint4& lo) {
    const float v[8] = {A.x, A.y, A.z, A.w, B.x, B.y, B.z, B.w};
    unsigned int h[8], q[8];
    #pragma unroll
    for (int i = 0; i < 8; ++i) {
        h[i] = bf16_rne(v[i]);
        q[i] = bf16_rne(v[i] - bf16f(h[i]));
    }
    hi = make_uint4(h[0] | (h[1] << 16), h[2] | (h[3] << 16),
                    h[4] | (h[5] << 16), h[6] | (h[7] << 16));
    lo = make_uint4(q[0] | (q[1] << 16), q[2] | (q[3] << 16),
                    q[4] | (q[5] << 16), q[6] | (q[7] << 16));
}

// Kernel 0: one-time W -> bf16 hi/lo split (2 groups x 256x256, 8 elems/thread).
__global__ __launch_bounds__(256)
void conv_w(const float* __restrict__ W1, const float* __restrict__ W2,
            unsigned short* __restrict__ Whi, unsigned short* __restrict__ Wlo)
{
    const int u    = blockIdx.x * 256 + threadIdx.x;   // 0..16383 (oct index)
    const int gidx = u >> 13;                          // 8192 octs per group
    const int rem  = u & 8191;
    const float* __restrict__ W = gidx ? W2 : W1;
    const float4 f0 = *(const float4*)&W[rem * 8];
    const float4 f1 = *(const float4*)&W[rem * 8 + 4];
    uint4 hi, lo;
    cvt8(f0, f1, hi, lo);
    *(uint4*)&Whi[gidx * 65536 + rem * 8] = hi;
    *(uint4*)&Wlo[gidx * 65536 + rem * 8] = lo;
}

// Kernel 1: t16[row][g*256+o] = bf16( clip( (x_g@W^T)[row][o]*softmax(a)[o] ) )
// ROUND-14: revert to r12's proven all-LDS per-chunk pipeline (best measured,
// ~24us; r13's direct-L2 B loads were sunk by the scheduler — VGPR=52 proof,
// 3rd occurrence) + DOUBLE-BUFFER with ONE barrier per chunk (T3-lite):
//   iter kc: STAGE(buf^1, kc+1) -> compute buf -> barrier
// DMA overlaps compute; barrier's vmcnt(0) drain waits only the remainder.
// Hazards: end-of-kc barrier orders all reads of buf before kc+1 overwrites
// it; stage(0) drains at softmax's internal barriers.
// LDS 41KB -> 3 blocks/CU (12 waves).  Swizzles identical to r12 (passed,
// bit-identical absmax): A granule kg^(row&7), B granule s^((row>>1)&3),
// both applied source-side + read-side (rule 21).
// C/D map: m89-verified col=lane&15, row=(lane>>4)*4+reg (validated r6-r13).
__global__ __launch_bounds__(256, 3)
void gemm_mfma(const float* __restrict__ x,
               const float* __restrict__ a1, const float* __restrict__ a2,
               const unsigned short* __restrict__ Whi,
               const unsigned short* __restrict__ Wlo,
               unsigned short* __restrict__ t16)
{
    const int slab = blockIdx.x;            // 32-row slab, 0..312 (last 16 phantom)
    const int cz   = blockIdx.y;            // col half (128 cols)
    const int g    = blockIdx.z;
    const float* __restrict__ a = g ? a2 : a1;
    const int tid = threadIdx.x;
    const int w   = tid >> 6;
    const int l   = tid & 63;

    __shared__ float          As[2][32 * 32];     // 2 x 4KB  fp32, swz granules
    __shared__ unsigned short Bhs[2][128 * 32];   // 2 x 8KB  bf16 hi
    __shared__ unsigned short Bls[2][128 * 32];   // 2 x 8KB  bf16 lo
    __shared__ float fwL[D];
    __shared__ float red[16];

    const unsigned short* __restrict__ WhiG = Whi + (g << 16);
    const unsigned short* __restrict__ WloG = Wlo + (g << 16);

    // staging source addresses (per-thread, constant across chunks except k)
    const int arloc = tid >> 3;                       // A dest row 0..31
    int agrow = slab * 32 + arloc;                    // clamp phantom rows
    if (agrow > N_NODES - 1) agrow = N_NODES - 1;
    const int akg   = (tid & 7) ^ (arloc & 7);        // inverse-swizzled granule
    const float* aSrcBase = &x[(size_t)agrow * XD + g * D + akg * 4];

    const int brloc0 = tid >> 2;                      // B dest row (call 0) 0..63
    const int brloc1 = brloc0 + 64;                   // call 1 row
    const int bkg0   = (tid & 3) ^ ((brloc0 >> 1) & 3);
    const int bkg1   = (tid & 3) ^ ((brloc1 >> 1) & 3);
    const unsigned short* bhSrc0 = &WhiG[(cz * 128 + brloc0) * 256 + bkg0 * 8];
    const unsigned short* bhSrc1 = &WhiG[(cz * 128 + brloc1) * 256 + bkg1 * 8];
    const unsigned short* blSrc0 = &WloG[(cz * 128 + brloc0) * 256 + bkg0 * 8];
    const unsigned short* blSrc1 = &WloG[(cz * 128 + brloc1) * 256 + bkg1 * 8];

    const int woff = w * 1024;                        // wave-uniform LDS call base

    #define STAGE(buf, kc)                                                     \
        do {                                                                   \
            gld_lds16(aSrcBase + (kc) * 32, (char*)As[buf]  + woff);           \
            gld_lds16(bhSrc0   + (kc) * 32, (char*)Bhs[buf] + woff);           \
            gld_lds16(bhSrc1   + (kc) * 32, (char*)Bhs[buf] + 4096 + woff);    \
            gld_lds16(blSrc0   + (kc) * 32, (char*)Bls[buf] + woff);           \
            gld_lds16(blSrc1   + (kc) * 32, (char*)Bls[buf] + 4096 + woff);    \
        } while (0)

    // ---- prologue: stage chunk 0 into buffer 0 (drains at softmax barriers) ----
    STAGE(0, 0);

    // ---- softmax(a) over 256 (block == 256 threads), redundantly per block ----
    {
        float v = a[tid];
        float m = v;
        #pragma unroll
        for (int o = 32; o; o >>= 1) m = fmaxf(m, __shfl_xor(m, o));
        if ((tid & 63) == 0) red[tid >> 6] = m;
        __syncthreads();
        m = fmaxf(fmaxf(red[0], red[1]), fmaxf(red[2], red[3]));
        float e = expf(v - m);
        float s = e;
        #pragma unroll
        for (int o = 32; o; o >>= 1) s += __shfl_xor(s, o);
        if ((tid & 63) == 0) red[4 + (tid >> 6)] = s;
        __syncthreads();
        s = red[4] + red[5] + red[6] + red[7];
        fwL[tid] = e / s;
    }
    __syncthreads();    // fwL visible; stage(0) DMA drained (vmcnt0 before barrier)

    f32x4 acc[4];
    #pragma unroll
    for (int i = 0; i < 4; ++i) acc[i] = (f32x4){0.f, 0.f, 0.f, 0.f};

    const int arow_l = 16 * (w >> 1) + (l & 15);      // wave's A row in tile
    const int s      = l >> 4;                        // k-slot 0..3 (8 elems)
    const int ct0    = (w & 1) * 4;                   // wave's 4 col-tiles

    #pragma unroll
    for (int kc = 0; kc < 8; ++kc) {
        const int cur = kc & 1;
        if (kc < 7) STAGE(cur ^ 1, kc + 1);   // prefetch next chunk, other buffer

        // ---- A fragment: 2 swizzled b128 reads -> cvt8 ----
        const int kg0 = (2 * s)     ^ (arow_l & 7);
        const int kg1 = (2 * s + 1) ^ (arow_l & 7);
        const float4 xa = *(const float4*)((const char*)As[cur] + arow_l * 128 + kg0 * 16);
        const float4 xb = *(const float4*)((const char*)As[cur] + arow_l * 128 + kg1 * 16);
        uint4 ahi, alo;
        cvt8(xa, xb, ahi, alo);
        const short8 ah = __builtin_bit_cast(short8, ahi);
        const short8 al = __builtin_bit_cast(short8, alo);

        #pragma unroll
        for (int i = 0; i < 4; ++i) {
            const int brow_l = (ct0 + i) * 16 + (l & 15);
            const int bkg    = s ^ ((brow_l >> 1) & 3);
            const short8 bh = __builtin_bit_cast(short8,
                *(const uint4*)((const char*)Bhs[cur] + brow_l * 64 + bkg * 16));
            const short8 bl = __builtin_bit_cast(short8,
                *(const uint4*)((const char*)Bls[cur] + brow_l * 64 + bkg * 16));
            acc[i] = __builtin_amdgcn_mfma_f32_16x16x32_bf16(ah, bh, acc[i], 0, 0, 0);
            acc[i] = __builtin_amdgcn_mfma_f32_16x16x32_bf16(al, bh, acc[i], 0, 0, 0);
            acc[i] = __builtin_amdgcn_mfma_f32_16x16x32_bf16(ah, bl, acc[i], 0, 0, 0);
        }
        __syncthreads();   // reads of buf[cur] done + stage(kc+1) landed
    }
    #undef STAGE

    // ---- epilogue: fw scale + hardtanh + bf16 store ----
    #pragma unroll
    for (int i = 0; i < 4; ++i) {
        const int   col = cz * 128 + (ct0 + i) * 16 + (l & 15);
        const float fw  = fwL[col];
        #pragma unroll
        for (int r = 0; r < 4; ++r) {
            const int row = slab * 32 + 16 * (w >> 1) + (l >> 4) * 4 + r;
            if (row < N_NODES)
                t16[(size_t)row * XD + g * D + col] =
                    (unsigned short)bf16_rne(clip1(acc[i][r] * fw));
        }
    }
}

// Kernel 2: SINGLE-PASS gather + Gaussian attention + aggregation, bf16 t.
// BYTE-IDENTICAL to round 9 (attribution: only gemm changes this round).
__global__ __launch_bounds__(256, 8)
void gat_aggregate(const unsigned short* __restrict__ t16,
                   const int* __restrict__ graph, float* __restrict__ out)
{
    const int n   = blockIdx.x;
    const int g   = blockIdx.y;
    const int tid = threadIdx.x;
    const int w   = tid >> 6;
    const int l   = tid & 63;

    __shared__ float part[4][D];    // per-wave partial weighted sums (4 KB)
    __shared__ float Ssh[4];        // per-wave partial exp-sums

    int rows[8];
    #pragma unroll
    for (int kk = 0; kk < 8; ++kk)
        rows[kk] = graph[(size_t)n * K_NB + (w + kk * 4)];

    const size_t gcol = (size_t)g * D + 4 * l;           // bf16 element index
    const uint2 ov = *(const uint2*)&t16[(size_t)n * XD + gcol];
    const float o0 = blo(ov.x), o1 = bhif(ov.x), o2 = blo(ov.y), o3 = bhif(ov.y);

    // batch all 8 gather loads before any use (8 outstanding 8B / lane)
    uint2 nbu[8];
    #pragma unroll
    for (int kk = 0; kk < 8; ++kk)
        nbu[kk] = *(const uint2*)&t16[(size_t)rows[kk] * XD + gcol];

    // unpack once; per-lane partial d2 for each of this wave's 8 k's
    float nf[8][4];
    float d2p[8];
    #pragma unroll
    for (int kk = 0; kk < 8; ++kk) {
        nf[kk][0] = blo(nbu[kk].x); nf[kk][1] = bhif(nbu[kk].x);
        nf[kk][2] = blo(nbu[kk].y); nf[kk][3] = bhif(nbu[kk].y);
        const float dx = o0 - nf[kk][0], dy = o1 - nf[kk][1];
        const float dz = o2 - nf[kk][2], dw = o3 - nf[kk][3];
        d2p[kk] = dx * dx + dy * dy + dz * dz + dw * dw;
    }

    // reduce-scatter over lane bits 0..2: lane l ends owning kk = l&7
    const bool b0 = l & 1, b1 = l & 2, b2 = l & 4;
    float u[4];
    #pragma unroll
    for (int i = 0; i < 4; ++i) {
        const float give = b0 ? d2p[2 * i] : d2p[2 * i + 1];
        const float keep = b0 ? d2p[2 * i + 1] : d2p[2 * i];
        u[i] = keep + __shfl_xor(give, 1);
    }
    float v[2];
    #pragma unroll
    for (int i = 0; i < 2; ++i) {
        const float give = b1 ? u[2 * i] : u[2 * i + 1];
        const float keep = b1 ? u[2 * i + 1] : u[2 * i];
        v[i] = keep + __shfl_xor(give, 2);
    }
    float d2 = (b2 ? v[1] : v[0]) + __shfl_xor(b2 ? v[0] : v[1], 4);
    // finish the 64-lane sum (kk = l&7 fixed, sum over the 8 lane-groups)
    d2 += __shfl_xor(d2, 8);
    d2 += __shfl_xor(d2, 16);
    d2 += __shfl_xor(d2, 32);

    const float e = __expf(-d2);          // ONE exp per lane (owns kk = l&7)

    // wave's exp-sum over its 8 k's (uniform in all lanes after 3 steps)
    float Sw = e;
    Sw += __shfl_xor(Sw, 1);
    Sw += __shfl_xor(Sw, 2);
    Sw += __shfl_xor(Sw, 4);

    // gather the 8 e's (ds_bpermute — LDS pipe) and accumulate
    const int base = l & 56;
    float4 p = make_float4(0.f, 0.f, 0.f, 0.f);
    #pragma unroll
    for (int kk = 0; kk < 8; ++kk) {
        const float ak = __shfl(e, base + kk);
        p.x += ak * nf[kk][0]; p.y += ak * nf[kk][1];
        p.z += ak * nf[kk][2]; p.w += ak * nf[kk][3];
    }

    *(float4*)&part[w][4 * l] = p;
    if (l == 0) Ssh[w] = Sw;
    __syncthreads();

    const float rS = 1.f / (Ssh[0] + Ssh[1] + Ssh[2] + Ssh[3]);
    const float y  = (part[0][tid] + part[1][tid] + part[2][tid] + part[3][tid]) * rS;
    out[(size_t)n * XD + (size_t)g * D + tid] = y;
}

extern "C" void kernel_launch(void* const* d_in, const int* in_sizes, int n_in,
                              void* d_out, int out_size, void* d_ws, size_t ws_size,
                              hipStream_t stream) {
    const float* x     = (const float*)d_in[0];
    const float* W1    = (const float*)d_in[1];
    const float* a1    = (const float*)d_in[2];
    const float* W2    = (const float*)d_in[3];
    const float* a2    = (const float*)d_in[4];
    const int*   graph = (const int*)d_in[5];
    float* out = (float*)d_out;

    // workspace layout: t16 bf16 (10.24 MB) | Whi (256 KB) | Wlo (256 KB)
    unsigned short* t16 = (unsigned short*)d_ws;
    unsigned short* Whi = t16 + (size_t)N_NODES * XD;
    unsigned short* Wlo = Whi + 2 * 65536;

    conv_w<<<64, 256, 0, stream>>>(W1, W2, Whi, Wlo);

    dim3 grid1(313, 2, 2);                            // (32-row slab, colhalf, group)
    gemm_mfma<<<grid1, 256, 0, stream>>>(x, a1, a2, Whi, Wlo, t16);

    dim3 grid2(N_NODES, 2);
    gat_aggregate<<<grid2, 256, 0, stream>>>(t16, graph, out);
}